// Round 5
// baseline (3735.654 us; speedup 1.0000x reference)
//
#include <hip/hip_runtime.h>

// LSTM: B=64, T=1024, D=512, H=512. Gate order i,f,g,o.
// Phase A: xW GEMM (f16 MFMA, bias folded in, f16 output).
// Phase B: persistent scan, 32 WGs x 512 thr = 4 row-groups(16 rows) x 8 slices(64 units).
//   Tag-in-data publish (f16 h | epoch<<16 dwords), triple-buffered, relaxed agent
//   atomics only (sc0 sc1 -> MALL-coherent), no fences/flags/RMW. s_sleep poll backoff.

#define B_  64
#define T_  1024
#define D_  512
#define H_  512
#define G4H 2048

typedef _Float16 half8 __attribute__((ext_vector_type(8)));
typedef float    f32x4 __attribute__((ext_vector_type(4)));
typedef unsigned long long ull;

static __device__ __forceinline__ float sigm(float x) { return 1.f / (1.f + __expf(-x)); }
static __device__ __forceinline__ float tanh_(float x) {
    float xc = fminf(fmaxf(x, -15.f), 15.f);
    float e  = __expf(2.f * xc);
    return (e - 1.f) / (e + 1.f);
}
static __device__ __forceinline__ float lo16f(unsigned u) {
    return (float)__builtin_bit_cast(_Float16, (unsigned short)(u & 0xffffu));
}
static __device__ __forceinline__ float hi16f(unsigned u) {
    return (float)__builtin_bit_cast(_Float16, (unsigned short)(u >> 16));
}

// ---------------- init: transpose-convert kernel -> WkT f16 [2048][512]
__global__ void init_kernel(const float* __restrict__ Wk, _Float16* __restrict__ WkT) {
    int idx = blockIdx.x * blockDim.x + threadIdx.x;
    int total = D_ * G4H;
    int stride = gridDim.x * blockDim.x;
    for (int i = idx; i < total; i += stride) {
        int k = i >> 11;
        int n = i & (G4H - 1);
        WkT[(size_t)n * D_ + k] = (_Float16)Wk[i];
    }
}

// ---------------- phase A: xw[t][b][col] = x[b][t][:] @ Wk[:][col] + bias[col], f16
__global__ __launch_bounds__(256) void gemm_xw(const float* __restrict__ x,
                                               const _Float16* __restrict__ WkT,
                                               const float* __restrict__ bias,
                                               _Float16* __restrict__ xw,
                                               int tbase) {
    __shared__ _Float16 As[64][40];
    __shared__ _Float16 Bst[64][40];
    const int tid  = threadIdx.x;
    const int lane = tid & 63;
    const int wave = tid >> 6;
    const int l15  = lane & 15;
    const int quad = lane >> 4;
    const int b     = blockIdx.z;
    const int n0    = blockIdx.x * 64;
    const int tloc0 = blockIdx.y * 64;

    const float* xbase = x + ((size_t)b * T_ + (tbase + tloc0)) * D_;
    f32x4 acc[4];
#pragma unroll
    for (int i = 0; i < 4; ++i) acc[i] = (f32x4){0.f, 0.f, 0.f, 0.f};

    const int ai = tid >> 2, ac = tid & 3;
    const int bn = tid >> 2, bq = tid & 3;

    for (int kb = 0; kb < 16; ++kb) {
        __syncthreads();
        const float* ap = xbase + (size_t)ai * D_ + kb * 32 + ac * 8;
        f32x4 av0 = *(const f32x4*)ap;
        f32x4 av1 = *(const f32x4*)(ap + 4);
        half8 ah = { (_Float16)av0.x, (_Float16)av0.y, (_Float16)av0.z, (_Float16)av0.w,
                     (_Float16)av1.x, (_Float16)av1.y, (_Float16)av1.z, (_Float16)av1.w };
        *(half8*)&As[ai][ac * 8] = ah;
        half8 bv = *(const half8*)(WkT + (size_t)(n0 + bn) * D_ + kb * 32 + bq * 8);
        *(half8*)&Bst[bn][bq * 8] = bv;
        __syncthreads();

        half8 afrag = *(const half8*)&As[16 * wave + l15][quad * 8];
#pragma unroll
        for (int nt = 0; nt < 4; ++nt) {
            half8 bfrag = *(const half8*)&Bst[nt * 16 + l15][quad * 8];
            acc[nt] = __builtin_amdgcn_mfma_f32_16x16x32_f16(afrag, bfrag, acc[nt], 0, 0, 0);
        }
    }
#pragma unroll
    for (int nt = 0; nt < 4; ++nt)
#pragma unroll
        for (int r = 0; r < 4; ++r) {
            int tt  = tloc0 + 16 * wave + quad * 4 + r;
            int col = n0 + nt * 16 + l15;
            xw[((size_t)tt * B_ + b) * G4H + col] = (_Float16)(acc[nt][r] + bias[col]);
        }
}

// ---------------- phase B: persistent scan, tag-in-data protocol
// 32 WGs x 512 thr. WG w: group g=w&3 (rows g*16..+15), slice s=w>>2 (units s*64..+63).
// Wave v: gate gv=v>>1, half hv=v&1 -> cols gv*512 + s*64 + hv*32 + {0..31}.
// hbuf: 3 slots x [64][512] tagged dwords (lo16 = h f16, hi16 = step+1).
__global__ __launch_bounds__(512, 1) void lstm_scan(const _Float16* __restrict__ xw,
                                                    const float* __restrict__ Wr,
                                                    unsigned* __restrict__ hbuf,
                                                    float* __restrict__ cio,
                                                    float* __restrict__ out,
                                                    int t0, int t1) {
    const int w    = blockIdx.x;
    const int g    = w & 3;
    const int s    = w >> 2;
    const int u0   = s * 64;
    const int tid  = threadIdx.x;
    const int lane = tid & 63;
    const int wave = tid >> 6;
    const int l15  = lane & 15;
    const int quad = lane >> 4;
    const int gv   = wave >> 1;      // gate of this wave
    const int hv   = wave & 1;       // which 32-col half

    // B-frags in registers: 2 col tiles of 16. 128 VGPRs.
    half8 bfrag[2][16];
#pragma unroll
    for (int ct = 0; ct < 2; ++ct) {
        const int col = gv * H_ + u0 + hv * 32 + ct * 16 + l15;
#pragma unroll
        for (int kt = 0; kt < 16; ++kt) {
            half8 v;
#pragma unroll
            for (int j = 0; j < 8; ++j)
                v[j] = (_Float16)Wr[(size_t)(kt * 32 + quad * 8 + j) * G4H + col];
            bfrag[ct][kt] = v;
        }
    }

    const int rho  = tid >> 5;        // batch-row in group (16)
    const int jj   = tid & 31;        // unit-pair in slice (32)
    const int brow = g * 16 + rho;
    const int un0  = u0 + 2 * jj;
    float c0 = 0.f, c1 = 0.f;
    if (t0 != 0) {
        c0 = cio[(size_t)brow * H_ + un0];
        c1 = cio[(size_t)brow * H_ + un0 + 1];
    }

    __shared__ _Float16 hS[16][520];     // group h slab [row][unit], pad 8
    __shared__ float    zS[16][260];     // z exchange [row][gate*64+lu], pad 4

    const size_t slotSz = (size_t)B_ * H_;   // dwords per slot

    for (int t = t0; t < t1; ++t) {
        // prefetch xw for this step (independent of h)
        const unsigned* xwd = (const unsigned*)(xw + ((size_t)(t - t0) * B_ + brow) * G4H);
        const int dbase = s * 32 + jj;
        unsigned xwi = xwd[0 * 256 + dbase];
        unsigned xwf = xwd[1 * 256 + dbase];
        unsigned xwg = xwd[2 * 256 + dbase];
        unsigned xwo = xwd[3 * 256 + dbase];

        if (t > 0) {
            // poll tagged slab: thread covers ulls tid + k*512 of the 4096-ull group slab
            const ull* src = (const ull*)(hbuf + (size_t)((t - 1) % 3) * slotSz)
                             + (size_t)(g * 16) * 256 + tid;
            const unsigned tgt = (unsigned)(t & 0xffff);
            const ull expect = ((ull)tgt << 16) | ((ull)tgt << 48);
            ull v[8];
            int guard = 0;
            while (true) {
                ull diff = 0;
#pragma unroll
                for (int k = 0; k < 8; ++k)
                    v[k] = __hip_atomic_load(src + (size_t)k * 512,
                                             __ATOMIC_RELAXED, __HIP_MEMORY_SCOPE_AGENT);
#pragma unroll
                for (int k = 0; k < 8; ++k)
                    diff |= (v[k] ^ expect) & 0xffff0000ffff0000ull;
                if (diff == 0) break;
                if (++guard > (1 << 14)) break;   // bailout: visible failure, not a hang
                __builtin_amdgcn_s_sleep(1);      // backoff: cut MALL poll spam
            }
            // strip tags, pack 2 f16 -> dword, stage to LDS
#pragma unroll
            for (int k = 0; k < 8; ++k) {
                int idx = k * 512 + tid;
                int row = idx >> 8, col = idx & 255;
                unsigned p = (unsigned)(v[k] & 0xffffu) | (((unsigned)(v[k] >> 32)) << 16);
                *(unsigned*)&hS[row][2 * col] = p;
            }
        }
        __syncthreads();   // BARRIER1: hS staged

        f32x4 a0 = {0.f,0.f,0.f,0.f}, a1 = a0, b0 = a0, b1 = a0;
        if (t > 0) {
#pragma unroll
            for (int kt = 0; kt < 16; kt += 2) {
                half8 af0 = *(const half8*)&hS[l15][kt * 32 + quad * 8];
                half8 af1 = *(const half8*)&hS[l15][(kt + 1) * 32 + quad * 8];
                a0 = __builtin_amdgcn_mfma_f32_16x16x32_f16(af0, bfrag[0][kt],     a0, 0, 0, 0);
                a1 = __builtin_amdgcn_mfma_f32_16x16x32_f16(af0, bfrag[1][kt],     a1, 0, 0, 0);
                b0 = __builtin_amdgcn_mfma_f32_16x16x32_f16(af1, bfrag[0][kt + 1], b0, 0, 0, 0);
                b1 = __builtin_amdgcn_mfma_f32_16x16x32_f16(af1, bfrag[1][kt + 1], b1, 0, 0, 0);
            }
        }
        f32x4 z0 = a0 + b0, z1 = a1 + b1;
        {
            const int bc = gv * 64 + hv * 32;   // local block col base
#pragma unroll
            for (int r = 0; r < 4; ++r) {
                zS[quad * 4 + r][bc + l15]      = z0[r];
                zS[quad * 4 + r][bc + 16 + l15] = z1[r];
            }
        }
        __syncthreads();   // BARRIER2: zS ready

        float zi0 = zS[rho][2*jj]       + lo16f(xwi), zi1 = zS[rho][2*jj + 1]       + hi16f(xwi);
        float zf0 = zS[rho][64 + 2*jj]  + lo16f(xwf), zf1 = zS[rho][64 + 2*jj + 1]  + hi16f(xwf);
        float zg0 = zS[rho][128 + 2*jj] + lo16f(xwg), zg1 = zS[rho][128 + 2*jj + 1] + hi16f(xwg);
        float zo0 = zS[rho][192 + 2*jj] + lo16f(xwo), zo1 = zS[rho][192 + 2*jj + 1] + hi16f(xwo);

        c0 = sigm(zf0) * c0 + sigm(zi0) * tanh_(zg0);
        c1 = sigm(zf1) * c1 + sigm(zi1) * tanh_(zg1);
        float h0 = sigm(zo0) * tanh_(c0);
        float h1 = sigm(zo1) * tanh_(c1);

        // tagged publish: one 8B relaxed agent store per thread
        const unsigned tagw = ((unsigned)((t + 1) & 0xffff)) << 16;
        unsigned d0 = (unsigned)__builtin_bit_cast(unsigned short, (_Float16)h0) | tagw;
        unsigned d1 = (unsigned)__builtin_bit_cast(unsigned short, (_Float16)h1) | tagw;
        ull wv = (ull)d0 | ((ull)d1 << 32);
        __hip_atomic_store((ull*)(hbuf + (size_t)(t % 3) * slotSz) + (size_t)brow * 256 + (un0 >> 1),
                           wv, __ATOMIC_RELAXED, __HIP_MEMORY_SCOPE_AGENT);

        if (t == T_ - 1) {
            out[(size_t)brow * H_ + un0]     = h0;
            out[(size_t)brow * H_ + un0 + 1] = h1;
        }
    }
    cio[(size_t)brow * H_ + un0]     = c0;
    cio[(size_t)brow * H_ + un0 + 1] = c1;
}

// ---------------- launch
extern "C" void kernel_launch(void* const* d_in, const int* in_sizes, int n_in,
                              void* d_out, int out_size, void* d_ws, size_t ws_size,
                              hipStream_t stream) {
    const float* x    = (const float*)d_in[0];
    const float* Wk   = (const float*)d_in[1];
    const float* Wr   = (const float*)d_in[2];
    const float* bias = (const float*)d_in[3];
    float* out = (float*)d_out;

    char* ws = (char*)d_ws;
    _Float16* WkT   = (_Float16*)(ws + 1024);                       // 2 MB
    unsigned* hbuf  = (unsigned*)(ws + 1024 + 2097152);             // 384 KB (3 slots)
    float*    cio   = (float*)  (ws + 1024 + 2097152 + 393216);     // 128 KB
    const size_t fixed = 1024 + 2097152 + 393216 + 131072;
    _Float16* xw    = (_Float16*)(ws + fixed);

    size_t avail = (ws_size > fixed) ? ws_size - fixed : 0;
    int ct = 0;
    const int cands[5] = {1024, 512, 256, 128, 64};
    for (int i = 0; i < 5; ++i) {
        if ((size_t)cands[i] * (size_t)(B_ * G4H * 2) <= avail) { ct = cands[i]; break; }
    }
    if (ct == 0) {
        hipMemsetAsync(d_out, 0, (size_t)out_size * 4, stream);
        return;
    }

    init_kernel<<<512, 256, 0, stream>>>(Wk, WkT);
    for (int t0 = 0; t0 < T_; t0 += ct) {
        gemm_xw<<<dim3(32, ct / 64, B_), 256, 0, stream>>>(x, WkT, bias, xw, t0);
        lstm_scan<<<32, 512, 0, stream>>>(xw, Wr, hbuf, cio, out, t0, t0 + ct);
    }
}